// Round 7
// baseline (105.555 us; speedup 1.0000x reference)
//
#include <hip/hip_runtime.h>
#include <hip/hip_bf16.h>

#define NTYPES 64
#define DIM 64
#define CAP 4096          // per-type perm region capacity
#define REPS 4            // diagnostic: reps 0..2 compute-only (laundered), rep 3 stores

typedef short bf16x8 __attribute__((ext_vector_type(8)));
typedef float f32x4  __attribute__((ext_vector_type(4)));

static __device__ __forceinline__ short f2bf(float f) {
    __hip_bfloat16 h = __float2bfloat16(f);   // RNE
    return *reinterpret_cast<short*>(&h);
}

// ---------------- K1: direct-claim scatter (grouped perm) + fused M transpose ------
__global__ void scatter_mtr_k(const int* __restrict__ types, int n,
                              int* __restrict__ cursor, int* __restrict__ perm,
                              const float* __restrict__ M, short* __restrict__ Mt) {
    __shared__ int lh[NTYPES];
    __shared__ int lbase[NTYPES];
    int tid = threadIdx.x;
    int bid = blockIdx.x;
    if (tid < NTYPES) lh[tid] = 0;
    __syncthreads();

    const int PER = 4;
    int base = bid * blockDim.x * PER;
    int myt[PER], myo[PER];
    #pragma unroll
    for (int k = 0; k < PER; ++k) {
        int i = base + k * blockDim.x + tid;      // coalesced
        if (i < n) {
            myt[k] = types[i];
            myo[k] = atomicAdd(&lh[myt[k]], 1);
        } else myt[k] = -1;
    }
    __syncthreads();
    if (tid < NTYPES) lbase[tid] = lh[tid] ? atomicAdd(&cursor[tid], lh[tid]) : 0;
    __syncthreads();
    #pragma unroll
    for (int k = 0; k < PER; ++k)
        if (myt[k] >= 0)
            perm[myt[k] * CAP + lbase[myt[k]] + myo[k]] = base + k * blockDim.x + tid;

    // ---- fused transpose: block t builds Mt[t][o][k] = bf16(M[t][k][o]) ----
    if (bid < NTYPES) {
        int t  = bid;
        int o  = tid >> 2;
        int ks = tid & 3;
        const float* Ms = M + ((size_t)t << 12);
        short vals[16];
        #pragma unroll
        for (int j = 0; j < 16; ++j)
            vals[j] = f2bf(Ms[(ks * 16 + j) * DIM + o]);
        short* dst = Mt + ((size_t)t << 12) + o * DIM + ks * 16;
        *(bf16x8*)(dst)     = *(const bf16x8*)(vals);
        *(bf16x8*)(dst + 8) = *(const bf16x8*)(vals + 8);
    }
}

// ---------------- K2: MFMA grouped GEMM, diagnostic REPS wrapper ----------------
__global__ __launch_bounds__(256) void main_k(const float* __restrict__ x,
                                              const short* __restrict__ Mt,
                                              const float* __restrict__ bias,
                                              const int* __restrict__ cursor,
                                              const int* __restrict__ perm,
                                              float* __restrict__ out) {
    int t = blockIdx.x;
    int cnt = cursor[t];
    if (cnt <= 0) return;

    int tid  = threadIdx.x;
    int lane = tid & 63;
    int wv   = tid >> 6;
    int col  = lane & 15;
    int hi   = lane >> 4;

    const short* At = Mt + ((size_t)t << 12);
    bf16x8 a0[4], a1[4];
    f32x4  bsv[4];
    #pragma unroll
    for (int ct = 0; ct < 4; ++ct) {
        const short* ar = At + (ct * 16 + col) * DIM + hi * 8;
        a0[ct] = *(const bf16x8*)(ar);
        a1[ct] = *(const bf16x8*)(ar + 32);
        bsv[ct] = *(const f32x4*)(bias + t * DIM + ct * 16 + hi * 4);
    }

    const int* pbase = perm + t * CAP;
    int nt = (cnt + 15) >> 4;

    for (int rep = 0; rep < REPS; ++rep) {
        bool last = (rep == REPS - 1);
        for (int tau = blockIdx.y * 4 + wv; tau < nt; tau += gridDim.y * 4) {
            int a = (tau << 4) + col;
            bool valid = a < cnt;
            if (!valid) a = cnt - 1;
            int g = pbase[a];
            asm volatile("" : "+v"(g));   // launder: forces fresh x loads each rep

            const float* xr = x + ((size_t)g << 6);
            float4 p0 = *(const float4*)(xr + hi * 8);
            float4 p1 = *(const float4*)(xr + hi * 8 + 4);
            float4 p2 = *(const float4*)(xr + 32 + hi * 8);
            float4 p3 = *(const float4*)(xr + 32 + hi * 8 + 4);
            bf16x8 b0, b1;
            b0[0] = f2bf(p0.x); b0[1] = f2bf(p0.y); b0[2] = f2bf(p0.z); b0[3] = f2bf(p0.w);
            b0[4] = f2bf(p1.x); b0[5] = f2bf(p1.y); b0[6] = f2bf(p1.z); b0[7] = f2bf(p1.w);
            b1[0] = f2bf(p2.x); b1[1] = f2bf(p2.y); b1[2] = f2bf(p2.z); b1[3] = f2bf(p2.w);
            b1[4] = f2bf(p3.x); b1[5] = f2bf(p3.y); b1[6] = f2bf(p3.z); b1[7] = f2bf(p3.w);

            f32x4 acc[4];
            #pragma unroll
            for (int ct = 0; ct < 4; ++ct) {
                acc[ct] = bsv[ct];
                acc[ct] = __builtin_amdgcn_mfma_f32_16x16x32_bf16(a0[ct], b0, acc[ct], 0, 0, 0);
                acc[ct] = __builtin_amdgcn_mfma_f32_16x16x32_bf16(a1[ct], b1, acc[ct], 0, 0, 0);
            }

            if (last) {
                if (valid) {
                    float* orow = out + ((size_t)g << 6);
                    #pragma unroll
                    for (int ct = 0; ct < 4; ++ct)
                        *(f32x4*)(orow + ct * 16 + hi * 4) = acc[ct];
                }
            } else {
                // keep the MFMA chains alive without stores (anti-DCE, rule #17)
                #pragma unroll
                for (int ct = 0; ct < 4; ++ct)
                    asm volatile("" :: "v"(acc[ct][0]));
            }
        }
    }
}

extern "C" void kernel_launch(void* const* d_in, const int* in_sizes, int n_in,
                              void* d_out, int out_size, void* d_ws, size_t ws_size,
                              hipStream_t stream) {
    const float* x     = (const float*)d_in[0];
    const int*   types = (const int*)d_in[1];
    const float* M     = (const float*)d_in[2];
    const float* bias  = (const float*)d_in[3];
    float* out = (float*)d_out;
    int n = in_sizes[1];

    // ws (ints): cursor[64] | pad->256 | perm[64*CAP] | Mt (bf16, 512KB)
    int* cursor = (int*)d_ws;
    int* perm   = cursor + 256;
    short* Mt   = (short*)(perm + NTYPES * CAP);

    hipMemsetAsync(cursor, 0, NTYPES * sizeof(int), stream);
    scatter_mtr_k<<<(n + 1023) / 1024, 256, 0, stream>>>(types, n, cursor, perm, M, Mt);
    main_k<<<dim3(NTYPES, 8), 256, 0, stream>>>(x, Mt, bias, cursor, perm, out);
}

// Round 8
// 94.225 us; speedup vs baseline: 1.1202x; 1.1202x over previous
//
#include <hip/hip_runtime.h>
#include <hip/hip_bf16.h>

#define NTYPES 64
#define DIM 64
#define CAP 4096          // per-type perm region capacity (max cnt ~1.7k)

typedef short bf16x8 __attribute__((ext_vector_type(8)));
typedef float f32x4  __attribute__((ext_vector_type(4)));

static __device__ __forceinline__ short f2bf(float f) {
    __hip_bfloat16 h = __float2bfloat16(f);   // RNE
    return *reinterpret_cast<short*>(&h);
}

// ---------------- K1: direct-claim scatter (grouped perm) + fused M transpose ------
__global__ void scatter_mtr_k(const int* __restrict__ types, int n,
                              int* __restrict__ cursor, int* __restrict__ perm,
                              const float* __restrict__ M, short* __restrict__ Mt) {
    __shared__ int lh[NTYPES];
    __shared__ int lbase[NTYPES];
    int tid = threadIdx.x;
    int bid = blockIdx.x;
    if (tid < NTYPES) lh[tid] = 0;
    __syncthreads();

    const int PER = 4;
    int i0 = bid * blockDim.x * PER + tid * PER;   // 16B-aligned int4 per thread
    int myt[PER], myo[PER];
    if (i0 + PER <= n) {
        int4 tv = *(const int4*)(types + i0);
        myt[0] = tv.x; myt[1] = tv.y; myt[2] = tv.z; myt[3] = tv.w;
        #pragma unroll
        for (int k = 0; k < PER; ++k) myo[k] = atomicAdd(&lh[myt[k]], 1);
    } else {
        #pragma unroll
        for (int k = 0; k < PER; ++k) {
            if (i0 + k < n) { myt[k] = types[i0 + k]; myo[k] = atomicAdd(&lh[myt[k]], 1); }
            else myt[k] = -1;
        }
    }
    __syncthreads();
    if (tid < NTYPES) lbase[tid] = lh[tid] ? atomicAdd(&cursor[tid], lh[tid]) : 0;
    __syncthreads();
    #pragma unroll
    for (int k = 0; k < PER; ++k)
        if (myt[k] >= 0)
            perm[myt[k] * CAP + lbase[myt[k]] + myo[k]] = i0 + k;

    // ---- fused transpose: block t builds Mt[t][o][k] = bf16(M[t][k][o]) ----
    if (bid < NTYPES) {
        int t  = bid;
        int o  = tid >> 2;
        int ks = tid & 3;
        const float* Ms = M + ((size_t)t << 12);
        short vals[16];
        #pragma unroll
        for (int j = 0; j < 16; ++j)
            vals[j] = f2bf(Ms[(ks * 16 + j) * DIM + o]);
        short* dst = Mt + ((size_t)t << 12) + o * DIM + ks * 16;
        *(bf16x8*)(dst)     = *(const bf16x8*)(vals);
        *(bf16x8*)(dst + 8) = *(const bf16x8*)(vals + 8);
    }
}

// ---------------- K2: MFMA grouped GEMM, 2-deep pipelined, 4 waves/SIMD ----------------
// grid = (64 types, 16 slots) x 256 thr = 4096 waves, <=2 tiles/wave.
// Wave-tile = 16 atoms x 64 outs; A (Mt) + bias hoisted to regs; prefetch of the
// next tile's perm+x overlaps the current tile's cvt+MFMA+store.
__global__ __launch_bounds__(256, 4) void main_k(const float* __restrict__ x,
                                                 const short* __restrict__ Mt,
                                                 const float* __restrict__ bias,
                                                 const int* __restrict__ cursor,
                                                 const int* __restrict__ perm,
                                                 float* __restrict__ out) {
    int t = blockIdx.x;
    int cnt = cursor[t];
    if (cnt <= 0) return;

    int tid  = threadIdx.x;
    int lane = tid & 63;
    int wv   = tid >> 6;
    int col  = lane & 15;
    int hi   = lane >> 4;

    const int* pbase = perm + t * CAP;
    int nt = (cnt + 15) >> 4;
    const int stride = gridDim.y * 4;
    int tau = blockIdx.y * 4 + wv;
    if (tau >= nt) return;

    // ---- hoist A fragments + bias (type-invariant) ----
    const short* At = Mt + ((size_t)t << 12);
    bf16x8 a0[4], a1[4];
    f32x4  bsv[4];
    #pragma unroll
    for (int ct = 0; ct < 4; ++ct) {
        const short* ar = At + (ct * 16 + col) * DIM + hi * 8;
        a0[ct] = *(const bf16x8*)(ar);
        a1[ct] = *(const bf16x8*)(ar + 32);
        bsv[ct] = *(const f32x4*)(bias + t * DIM + ct * 16 + hi * 4);
    }

    // ---- prologue: loads for first tile ----
    int a = (tau << 4) + col;
    bool valid = a < cnt;
    if (!valid) a = cnt - 1;
    int g = pbase[a];
    const float* xr = x + ((size_t)g << 6);
    float4 p0 = *(const float4*)(xr + hi * 8);
    float4 p1 = *(const float4*)(xr + hi * 8 + 4);
    float4 p2 = *(const float4*)(xr + 32 + hi * 8);
    float4 p3 = *(const float4*)(xr + 32 + hi * 8 + 4);

    while (true) {
        // ---- prefetch next tile (independent of current compute) ----
        int tau_n = tau + stride;
        bool have_n = tau_n < nt;
        int g_n = 0; bool valid_n = false;
        float4 q0, q1, q2, q3;
        if (have_n) {
            int an = (tau_n << 4) + col;
            valid_n = an < cnt;
            if (!valid_n) an = cnt - 1;
            g_n = pbase[an];
            const float* xrn = x + ((size_t)g_n << 6);
            q0 = *(const float4*)(xrn + hi * 8);
            q1 = *(const float4*)(xrn + hi * 8 + 4);
            q2 = *(const float4*)(xrn + 32 + hi * 8);
            q3 = *(const float4*)(xrn + 32 + hi * 8 + 4);
        }

        // ---- convert + compute current tile ----
        bf16x8 b0, b1;
        b0[0] = f2bf(p0.x); b0[1] = f2bf(p0.y); b0[2] = f2bf(p0.z); b0[3] = f2bf(p0.w);
        b0[4] = f2bf(p1.x); b0[5] = f2bf(p1.y); b0[6] = f2bf(p1.z); b0[7] = f2bf(p1.w);
        b1[0] = f2bf(p2.x); b1[1] = f2bf(p2.y); b1[2] = f2bf(p2.z); b1[3] = f2bf(p2.w);
        b1[4] = f2bf(p3.x); b1[5] = f2bf(p3.y); b1[6] = f2bf(p3.z); b1[7] = f2bf(p3.w);

        f32x4 acc[4];
        #pragma unroll
        for (int ct = 0; ct < 4; ++ct) {
            acc[ct] = bsv[ct];
            acc[ct] = __builtin_amdgcn_mfma_f32_16x16x32_bf16(a0[ct], b0, acc[ct], 0, 0, 0);
            acc[ct] = __builtin_amdgcn_mfma_f32_16x16x32_bf16(a1[ct], b1, acc[ct], 0, 0, 0);
        }

        if (valid) {
            float* orow = out + ((size_t)g << 6);
            #pragma unroll
            for (int ct = 0; ct < 4; ++ct)
                __builtin_nontemporal_store(acc[ct], (f32x4*)(orow + ct * 16 + hi * 4));
        }

        if (!have_n) break;
        tau = tau_n; g = g_n; valid = valid_n;
        p0 = q0; p1 = q1; p2 = q2; p3 = q3;
    }
}

extern "C" void kernel_launch(void* const* d_in, const int* in_sizes, int n_in,
                              void* d_out, int out_size, void* d_ws, size_t ws_size,
                              hipStream_t stream) {
    const float* x     = (const float*)d_in[0];
    const int*   types = (const int*)d_in[1];
    const float* M     = (const float*)d_in[2];
    const float* bias  = (const float*)d_in[3];
    float* out = (float*)d_out;
    int n = in_sizes[1];

    // ws (ints): cursor[64] | pad->256 | perm[64*CAP] | Mt (bf16, 512KB)
    int* cursor = (int*)d_ws;
    int* perm   = cursor + 256;
    short* Mt   = (short*)(perm + NTYPES * CAP);

    hipMemsetAsync(cursor, 0, NTYPES * sizeof(int), stream);
    scatter_mtr_k<<<(n + 1023) / 1024, 256, 0, stream>>>(types, n, cursor, perm, M, Mt);
    main_k<<<dim3(NTYPES, 16), 256, 0, stream>>>(x, Mt, bias, cursor, perm, out);
}